// Round 11
// baseline (92.081 us; speedup 1.0000x reference)
//
#include <hip/hip_runtime.h>
#include <hip/hip_bf16.h>
#include <math.h>

// Problem constants
#define BB 8
#define SS 1024
#define INDIM 512
#define ED 512
#define NH 8
#define HD 64

typedef __attribute__((ext_vector_type(8))) short short8;
typedef __attribute__((ext_vector_type(4))) float f32x4;
typedef __attribute__((ext_vector_type(16))) float f32x16;
typedef unsigned short u16;

typedef __attribute__((address_space(1))) const void gv_t;
typedef __attribute__((address_space(3))) void lv_t;

static __device__ __forceinline__ u16 f2bf(float f) {
  union { float f; unsigned u; } v; v.f = f;
  unsigned r = v.u + 0x7fffu + ((v.u >> 16) & 1u);
  return (u16)(r >> 16);
}

// packed f32x2 -> bf16x2 (RTNE), single VOP3 instr on gfx950
static __device__ __forceinline__ unsigned cvt_pk_bf16(float a, float b) {
  unsigned r;
  asm("v_cvt_pk_bf16_f32 %0, %1, %2" : "=v"(r) : "v"(a), "v"(b));
  return r;
}
// v_exp_f32 = 2^x natively
static __device__ __forceinline__ float fast_exp2(float x) {
  float r; asm("v_exp_f32 %0, %1" : "=v"(r) : "v"(x)); return r;
}

// ---------------- fp32 -> bf16 convert (all three inputs, one launch) ------
__global__ void cvt_all(const float* __restrict__ x, const float* __restrict__ wq,
                        const float* __restrict__ wo, u16* __restrict__ xb,
                        u16* __restrict__ wqb, u16* __restrict__ wob) {
  const int n1 = 1048576;            // x: 4194304/4 quads
  const int n2 = n1 + 196608;        // wqkv: 786432/4
  const int n3 = n2 + 65536;         // wo: 262144/4
  int i = blockIdx.x * blockDim.x + threadIdx.x;
  int stride = gridDim.x * blockDim.x;
  for (; i < n3; i += stride) {
    const float4* src; ushort4* dst; int j;
    if (i < n1)      { src = (const float4*)x;  dst = (ushort4*)xb;  j = i; }
    else if (i < n2) { src = (const float4*)wq; dst = (ushort4*)wqb; j = i - n1; }
    else             { src = (const float4*)wo; dst = (ushort4*)wob; j = i - n2; }
    float4 v = src[j];
    ushort4 o;
    o.x = f2bf(v.x); o.y = f2bf(v.y); o.z = f2bf(v.z); o.w = f2bf(v.w);
    dst[j] = o;
  }
}

// ---------------- NT GEMM: C[M,N] = A[M,K] * B[N,K]^T (bf16 in, MFMA) -------
// (R7-measured-best form: single-buffer 32 KB LDS, 3 blocks/CU for gemm0.)
// Staging: global_load_lds width=16 into linear [128][64] LDS, XOR-swizzled
// source (c8 ^= row&7) + same XOR on ds_read (both-sides-or-neither rule).
// EPI==0: QKV projection epilogue -> scatter to q (x 0.125*log2e), k, vt layouts
// EPI==1: O projection, raw fp32 out + per-block LN partials (no sync)
template<int EPI>
__global__ __launch_bounds__(256, 2)
void gemm_nt(const u16* __restrict__ A, const u16* __restrict__ Bm, int K,
             float* __restrict__ outF,
             u16* __restrict__ qws, u16* __restrict__ kws, u16* __restrict__ vtws,
             float2* __restrict__ partials)
{
  __shared__ u16 As[128][64];
  __shared__ u16 Bs[128][64];
  const int tid = threadIdx.x;
  const int lane = tid & 63;
  const int wv = tid >> 6;
  const int wr = wv >> 1, wc = wv & 1;
  const int bm = blockIdx.x, bn = blockIdx.y;
  const int l15 = lane & 15, lg = lane >> 4;
  const int srow8 = lane >> 3;   // 0..7 within an 8-row staging stripe
  const int sc8 = lane & 7;      // 16B column within row

  f32x4 acc[4][4];
  #pragma unroll
  for (int i = 0; i < 4; i++)
    #pragma unroll
    for (int j = 0; j < 4; j++) acc[i][j] = (f32x4){0.f, 0.f, 0.f, 0.f};

  for (int kk = 0; kk < K; kk += 64) {
    // ---- async stage A/B tiles: 4 issues/wave each, 1KB per wave-issue ----
    #pragma unroll
    for (int i = 0; i < 4; i++) {
      int r0 = (i * 4 + wv) * 8;
      int r = r0 + srow8;
      int cs = sc8 ^ (r & 7);
      const u16* ga = A + (size_t)(bm * 128 + r) * K + kk + cs * 8;
      __builtin_amdgcn_global_load_lds((gv_t*)ga, (lv_t*)&As[r0][0], 16, 0, 0);
      const u16* gb = Bm + (size_t)(bn * 128 + r) * K + kk + cs * 8;
      __builtin_amdgcn_global_load_lds((gv_t*)gb, (lv_t*)&Bs[r0][0], 16, 0, 0);
    }
    __syncthreads();   // compiler inserts vmcnt(0) drain before barrier
    #pragma unroll
    for (int kc = 0; kc < 2; kc++) {
      short8 af[4], bf[4];
      #pragma unroll
      for (int mi = 0; mi < 4; mi++) {
        int ra = wr * 64 + mi * 16 + l15;
        af[mi] = *(const short8*)&As[ra][((kc * 4 + lg) ^ (ra & 7)) * 8];
      }
      #pragma unroll
      for (int ni = 0; ni < 4; ni++) {
        int rb = wc * 64 + ni * 16 + l15;
        bf[ni] = *(const short8*)&Bs[rb][((kc * 4 + lg) ^ (rb & 7)) * 8];
      }
      #pragma unroll
      for (int mi = 0; mi < 4; mi++)
        #pragma unroll
        for (int ni = 0; ni < 4; ni++)
          acc[mi][ni] = __builtin_amdgcn_mfma_f32_16x16x32_bf16(af[mi], bf[ni], acc[mi][ni], 0, 0, 0);
    }
    __syncthreads();
  }

  // ---- epilogue; C-frag: col = lane&15, row = (lane>>4)*4 + r ----
  if (EPI == 0) {
    #pragma unroll
    for (int mi = 0; mi < 4; mi++) {
      int rowg = bm * 128 + wr * 64 + mi * 16 + lg * 4;
      #pragma unroll
      for (int ni = 0; ni < 4; ni++) {
        int colg = bn * 128 + wc * 64 + ni * 16 + l15;
        #pragma unroll
        for (int r = 0; r < 4; r++) {
          int rg = rowg + r;
          float v = acc[mi][ni][r];
          int b = rg >> 10, s = rg & 1023;
          int h = colg / 192, c = colg - h * 192;
          int bh = b * 8 + h;
          if (c < 64)
            qws[((size_t)(bh * 1024 + s)) * 64 + c] = f2bf(v * 0.18033688f); // 0.125*log2(e)
          else if (c < 128)
            kws[((size_t)(bh * 1024 + s)) * 64 + (c - 64)] = f2bf(v);
          else
            vtws[((size_t)(bh * 64 + (c - 128))) * 1024 + s] = f2bf(v);
        }
      }
    }
  } else {
    // raw output write + per-block LN partial sums (plain store, no sync)
    float s1 = 0.f, s2 = 0.f;
    #pragma unroll
    for (int mi = 0; mi < 4; mi++) {
      int rowg = bm * 128 + wr * 64 + mi * 16 + lg * 4;
      #pragma unroll
      for (int ni = 0; ni < 4; ni++) {
        int colg = bn * 128 + wc * 64 + ni * 16 + l15;
        #pragma unroll
        for (int r = 0; r < 4; r++) {
          float v = acc[mi][ni][r];
          s1 += v; s2 += v * v;
          outF[(size_t)(rowg + r) * 512 + colg] = v;
        }
      }
    }
    #pragma unroll
    for (int off = 1; off < 64; off <<= 1) {
      s1 += __shfl_xor(s1, off);
      s2 += __shfl_xor(s2, off);
    }
    __shared__ float r1[4], r2[4];
    if (lane == 0) { r1[wv] = s1; r2[wv] = s2; }
    __syncthreads();
    if (tid == 0) {
      float t1 = r1[0] + r1[1] + r1[2] + r1[3];
      float t2 = r2[0] + r2[1] + r2[2] + r2[3];
      partials[bm * 4 + bn] = make_float2(t1, t2);
    }
  }
}

// ---------------- Flash attention, split-KV x2, 32x32 swapped-QK^T --------
// 1024 blocks = 64 bh * 8 q-tiles(128 q) * 2 KV-halves, XCD-swizzled (one bh
// per XCD). 4 waves * 32 q rows; KVBLK=64 dbuf; LDS 36.9 KB -> 4 blocks/CU
// -> ALL blocks co-resident -> 4 waves/SIMD (2x the non-split TLP).
// Each half writes normalized O (bf16) + per-row (m,l); merge combines.
// Logits in log2 units (Q pre-scaled by 0.125*log2e).
__global__ __launch_bounds__(256, 4)
void attn_kernel(const u16* __restrict__ qws, const u16* __restrict__ kws,
                 const u16* __restrict__ vtws, u16* __restrict__ opart,
                 float2* __restrict__ mlbuf)
{
  __shared__ __align__(16) u16 Ksm[2][64][72];   // K tile [k][d], dbuf
  __shared__ __align__(16) u16 Vsm[2][64][72];   // V tile [d][k], dbuf
  const int tid = threadIdx.x;
  const int lane = tid & 63;
  const int wq = tid >> 6;          // wave id 0..3, 32 q rows each
  const int l31 = lane & 31;
  const int hi = lane >> 5;
  // XCD swizzle: 1024 blocks -> 128 consecutive logical blocks per XCD
  const int logical = (blockIdx.x & 7) * 128 + (blockIdx.x >> 3);
  const int bh = logical >> 4;             // 16 blocks per bh
  const int qt = (logical >> 1) & 7;
  const int half = logical & 1;
  const int q0 = qt * 128;
  const int kv0 = half * 512;

  // ---- Q B-frags from global: col=q=l31, k-dim d = 16j+8hi+e ----
  short8 qf[4];
  {
    const u16* qp = qws + ((size_t)bh * 1024 + q0 + wq * 32 + l31) * 64 + 8 * hi;
    #pragma unroll
    for (int j = 0; j < 4; j++) qf[j] = *(const short8*)(qp + 16 * j);
  }

  // ---- stage K/V tile 0 (256 threads: two uint4 each per tile) ----
  const int srow = tid >> 3;             // 0..31
  const int sc8 = (tid & 7) * 8;
  uint4 kreg[2], vreg[2];
  kreg[0] = *(const uint4*)(kws + ((size_t)bh * 1024 + kv0 + srow) * 64 + sc8);
  kreg[1] = *(const uint4*)(kws + ((size_t)bh * 1024 + kv0 + srow + 32) * 64 + sc8);
  vreg[0] = *(const uint4*)(vtws + ((size_t)(bh * 64 + srow)) * 1024 + kv0 + sc8);
  vreg[1] = *(const uint4*)(vtws + ((size_t)(bh * 64 + srow + 32)) * 1024 + kv0 + sc8);
  *(uint4*)&Ksm[0][srow][sc8] = kreg[0];
  *(uint4*)&Ksm[0][srow + 32][sc8] = kreg[1];
  *(uint4*)&Vsm[0][srow][sc8] = vreg[0];
  *(uint4*)&Vsm[0][srow + 32][sc8] = vreg[1];
  __syncthreads();

  f32x16 o[2];
  #pragma unroll
  for (int r = 0; r < 16; r++) { o[0][r] = 0.f; o[1][r] = 0.f; }
  float m = -1e30f, l = 0.f;

  for (int t = 0; t < 8; t++) {
    const int cur = t & 1;
    // T14: issue next-tile global loads first (latency hides under compute)
    if (t < 7) {
      int kv = kv0 + (t + 1) * 64;
      kreg[0] = *(const uint4*)(kws + ((size_t)bh * 1024 + kv + srow) * 64 + sc8);
      kreg[1] = *(const uint4*)(kws + ((size_t)bh * 1024 + kv + srow + 32) * 64 + sc8);
      vreg[0] = *(const uint4*)(vtws + ((size_t)(bh * 64 + srow)) * 1024 + kv + sc8);
      vreg[1] = *(const uint4*)(vtws + ((size_t)(bh * 64 + srow + 32)) * 1024 + kv + sc8);
    }

    // ---- S^T = K * Q^T: C[row=k_local][col=q=l31] per 32-key subtile ----
    f32x16 stv[2];
    __builtin_amdgcn_s_setprio(1);
    #pragma unroll
    for (int s2 = 0; s2 < 2; s2++) {
      f32x16 c;
      #pragma unroll
      for (int r = 0; r < 16; r++) c[r] = 0.f;
      #pragma unroll
      for (int j = 0; j < 4; j++) {
        short8 kf = *(const short8*)&Ksm[cur][s2 * 32 + l31][16 * j + 8 * hi];
        c = __builtin_amdgcn_mfma_f32_32x32x16_bf16(kf, qf[j], c, 0, 0, 0);
      }
      stv[s2] = c;
    }
    __builtin_amdgcn_s_setprio(0);

    // ---- online softmax: lane owns q=l31, 32 of 64 k's (other half at lane^32)
    float mx[16];
    #pragma unroll
    for (int r = 0; r < 16; r++) mx[r] = fmaxf(stv[0][r], stv[1][r]);
    #pragma unroll
    for (int w = 8; w >= 1; w >>= 1)
      #pragma unroll
      for (int r = 0; r < w; r++) mx[r] = fmaxf(mx[r], mx[r + w]);
    float pm = fmaxf(mx[0], __shfl_xor(mx[0], 32));

    // T13 defer-max (log2 units)
    if (!__all(pm - m <= 10.0f)) {
      float mn = fmaxf(m, pm);
      float al = fast_exp2(m - mn);
      m = mn; l *= al;
      #pragma unroll
      for (int reg = 0; reg < 16; reg++) {
        int qrow = (reg & 3) + 8 * (reg >> 2) + 4 * hi;
        float alo = __shfl(al, qrow);
        o[0][reg] *= alo; o[1][reg] *= alo;
      }
    }

    unsigned pk[16];
    float ps[16];
    #pragma unroll
    for (int s2 = 0; s2 < 2; s2++)
      #pragma unroll
      for (int j = 0; j < 8; j++) {
        float p0 = fast_exp2(stv[s2][2 * j] - m);
        float p1 = fast_exp2(stv[s2][2 * j + 1] - m);
        ps[s2 * 8 + j] = p0 + p1;
        pk[s2 * 8 + j] = cvt_pk_bf16(p0, p1);
      }
    #pragma unroll
    for (int w = 8; w >= 1; w >>= 1)
      #pragma unroll
      for (int r = 0; r < w; r++) ps[r] += ps[r + w];
    l += ps[0] + __shfl_xor(ps[0], 32);

    // ---- P redistribution: 8 permlane32_swap build PV A-frags in-register ----
    short8 pa[4];
    #pragma unroll
    for (int cc = 0; cc < 4; cc++) {
      int base = (cc >> 1) * 8 + (cc & 1) * 4;
      unsigned a0 = pk[base + 0], a2 = pk[base + 2];
      unsigned a1 = pk[base + 1], a3 = pk[base + 3];
      asm volatile("v_permlane32_swap_b32 %0, %1" : "+v"(a0), "+v"(a2));
      asm volatile("v_permlane32_swap_b32 %0, %1" : "+v"(a1), "+v"(a3));
      union { unsigned u[4]; short8 s8; } uu;
      uu.u[0] = a0; uu.u[1] = a1; uu.u[2] = a2; uu.u[3] = a3;
      pa[cc] = uu.s8;
    }

    // ---- O += P * V : A=P[q][k], B=V[k][d] (from Vt rows) ----
    __builtin_amdgcn_s_setprio(1);
    #pragma unroll
    for (int dh = 0; dh < 2; dh++)
      #pragma unroll
      for (int cc = 0; cc < 4; cc++) {
        short8 vf = *(const short8*)&Vsm[cur][dh * 32 + l31][16 * cc + 8 * hi];
        o[dh] = __builtin_amdgcn_mfma_f32_32x32x16_bf16(pa[cc], vf, o[dh], 0, 0, 0);
      }
    __builtin_amdgcn_s_setprio(0);

    // ---- write next tile into other buffer ----
    if (t < 7) {
      *(uint4*)&Ksm[cur ^ 1][srow][sc8] = kreg[0];
      *(uint4*)&Ksm[cur ^ 1][srow + 32][sc8] = kreg[1];
      *(uint4*)&Vsm[cur ^ 1][srow][sc8] = vreg[0];
      *(uint4*)&Vsm[cur ^ 1][srow + 32][sc8] = vreg[1];
    }
    __syncthreads();
  }

  // ---- epilogue: normalized partial O (bf16) + (m, l) per q row ----
  const size_t qbase = (size_t)half * 65536 + (size_t)bh * 1024 + q0 + wq * 32;
  if (hi == 0)
    mlbuf[qbase + l31] = make_float2(m, l);
  #pragma unroll
  for (int reg = 0; reg < 16; reg++) {
    int qrow = (reg & 3) + 8 * (reg >> 2) + 4 * hi;
    float linv = 1.0f / __shfl(l, qrow);
    size_t grow = (qbase + qrow) * 64;
    opart[grow + l31]      = f2bf(o[0][reg] * linv);
    opart[grow + 32 + l31] = f2bf(o[1][reg] * linv);
  }
}

// ---------------- split-KV merge: combine the 2 halves into vals -----------
// 2048 blocks x 256 threads; thread handles 8 d of one q row.
__global__ void attn_merge(const u16* __restrict__ opart,
                           const float2* __restrict__ mlbuf,
                           u16* __restrict__ vals)
{
  int idx = blockIdx.x * 256 + threadIdx.x;    // 524288 total
  int q = idx >> 3;                            // global q row 0..65535
  int d8 = (idx & 7) * 8;
  float2 ml0 = mlbuf[q];
  float2 ml1 = mlbuf[65536 + q];
  float M = fmaxf(ml0.x, ml1.x);
  float w0 = ml0.y * fast_exp2(ml0.x - M);
  float w1 = ml1.y * fast_exp2(ml1.x - M);
  float inv = 1.0f / (w0 + w1);
  w0 *= inv; w1 *= inv;
  ushort4 a0 = *(const ushort4*)(opart + (size_t)q * 64 + d8);
  ushort4 a1 = *(const ushort4*)(opart + (size_t)q * 64 + d8 + 4);
  ushort4 b0 = *(const ushort4*)(opart + (size_t)(65536 + q) * 64 + d8);
  ushort4 b1 = *(const ushort4*)(opart + (size_t)(65536 + q) * 64 + d8 + 4);
  const u16* ap = (const u16*)&a0;  // a0,a1 contiguous? combine manually
  ushort4 o0, o1;
  {
    u16 av[8] = {a0.x, a0.y, a0.z, a0.w, a1.x, a1.y, a1.z, a1.w};
    u16 bv[8] = {b0.x, b0.y, b0.z, b0.w, b1.x, b1.y, b1.z, b1.w};
    u16 ov[8];
    #pragma unroll
    for (int j = 0; j < 8; j++) {
      union { unsigned u; float f; } fa, fb;
      fa.u = (unsigned)av[j] << 16;
      fb.u = (unsigned)bv[j] << 16;
      ov[j] = f2bf(w0 * fa.f + w1 * fb.f);
    }
    o0 = make_ushort4(ov[0], ov[1], ov[2], ov[3]);
    o1 = make_ushort4(ov[4], ov[5], ov[6], ov[7]);
  }
  (void)ap;
  // vals[b, s, h*64+d]
  int bh = q >> 10, s = q & 1023;
  int b = bh >> 3, h = bh & 7;
  size_t vbase = ((size_t)(b * 1024 + s)) * 512 + h * 64 + d8;
  *(ushort4*)(vals + vbase) = o0;
  *(ushort4*)(vals + vbase + 4) = o1;
}

// ------- LayerNorm: each block reduces its batch's 32 partials, normalizes --
__global__ void ln_norm2(float* __restrict__ o, const float2* __restrict__ partials) {
  const int blk = blockIdx.x;        // 2048 blocks; 256 per batch
  const int b = blk >> 8;
  const int lane = threadIdx.x & 63;
  float s1 = 0.f, s2 = 0.f;
  if (lane < 32) {
    float2 p = partials[b * 32 + lane];
    s1 = p.x; s2 = p.y;
  }
  #pragma unroll
  for (int off = 1; off < 64; off <<= 1) {
    s1 += __shfl_xor(s1, off);
    s2 += __shfl_xor(s2, off);
  }
  float mu = s1 / 524288.f;
  float rs = rsqrtf(s2 / 524288.f - mu * mu + 1e-5f);
  const int base = blk * 512;        // 512 float4 per block
  #pragma unroll
  for (int k = 0; k < 2; k++) {
    int i = base + threadIdx.x + k * 256;
    float4 v = ((const float4*)o)[i];
    v.x = (v.x - mu) * rs; v.y = (v.y - mu) * rs;
    v.z = (v.z - mu) * rs; v.w = (v.w - mu) * rs;
    ((float4*)o)[i] = v;
  }
}

extern "C" void kernel_launch(void* const* d_in, const int* in_sizes, int n_in,
                              void* d_out, int out_size, void* d_ws, size_t ws_size,
                              hipStream_t stream) {
  const float* x = (const float*)d_in[0];
  const float* wqkv = (const float*)d_in[1];
  const float* wo = (const float*)d_in[2];
  float* out = (float*)d_out;
  char* ws = (char*)d_ws;

  u16* xb        = (u16*)(ws + 0);          // 8192*512   bf16 =  8,388,608 B
  u16* wqb       = (u16*)(ws + 8388608);    // 1536*512   bf16 =  1,572,864 B
  u16* wob       = (u16*)(ws + 9961472);    // 512*512    bf16 =    524,288 B
  u16* qws       = (u16*)(ws + 10485760);   // [bh,1024,64]    =  8,388,608 B
  u16* kws       = (u16*)(ws + 18874368);   // [bh,1024,64]    =  8,388,608 B
  u16* vtws      = (u16*)(ws + 27262976);   // [bh,64,1024]    =  8,388,608 B
  u16* opart     = (u16*)(ws + 35651584);   // [2,65536,64] bf16 = 16,777,216 B
  float2* mlbuf  = (float2*)(ws + 52428800);// [2,65536] float2 =  1,048,576 B
  u16* vals      = (u16*)(ws + 53477376);   // [8192,512] bf16  =  8,388,608 B
  float2* parts  = (float2*)(ws + 61865984);// 256 float2 = 2 KB

  cvt_all<<<1280, 256, 0, stream>>>(x, wqkv, wo, xb, wqb, wob);

  dim3 g1(64, 12);
  gemm_nt<0><<<g1, 256, 0, stream>>>(xb, wqb, 512, nullptr, qws, kws, vtws, nullptr);

  attn_kernel<<<1024, 256, 0, stream>>>(qws, kws, vtws, opart, mlbuf);
  attn_merge<<<2048, 256, 0, stream>>>(opart, mlbuf, vals);

  dim3 g2(64, 4);
  gemm_nt<1><<<g2, 256, 0, stream>>>(vals, wob, 512, out, nullptr, nullptr, nullptr, parts);

  ln_norm2<<<2048, 256, 0, stream>>>(out, parts);
}

// Round 12
// 82.450 us; speedup vs baseline: 1.1168x; 1.1168x over previous
//
#include <hip/hip_runtime.h>
#include <hip/hip_bf16.h>
#include <math.h>

// Problem constants
#define BB 8
#define SS 1024
#define INDIM 512
#define ED 512
#define NH 8
#define HD 64

typedef __attribute__((ext_vector_type(8))) short short8;
typedef __attribute__((ext_vector_type(4))) float f32x4;
typedef __attribute__((ext_vector_type(16))) float f32x16;
typedef unsigned short u16;

typedef __attribute__((address_space(1))) const void gv_t;
typedef __attribute__((address_space(3))) void lv_t;

static __device__ __forceinline__ u16 f2bf(float f) {
  union { float f; unsigned u; } v; v.f = f;
  unsigned r = v.u + 0x7fffu + ((v.u >> 16) & 1u);
  return (u16)(r >> 16);
}

// packed f32x2 -> bf16x2 (RTNE), single VOP3 instr on gfx950
static __device__ __forceinline__ unsigned cvt_pk_bf16(float a, float b) {
  unsigned r;
  asm("v_cvt_pk_bf16_f32 %0, %1, %2" : "=v"(r) : "v"(a), "v"(b));
  return r;
}
// v_exp_f32 = 2^x natively
static __device__ __forceinline__ float fast_exp2(float x) {
  float r; asm("v_exp_f32 %0, %1" : "=v"(r) : "v"(x)); return r;
}

// ---------------- fp32 -> bf16 convert (all three inputs, one launch) ------
__global__ void cvt_all(const float* __restrict__ x, const float* __restrict__ wq,
                        const float* __restrict__ wo, u16* __restrict__ xb,
                        u16* __restrict__ wqb, u16* __restrict__ wob) {
  const int n1 = 1048576;            // x: 4194304/4 quads
  const int n2 = n1 + 196608;        // wqkv: 786432/4
  const int n3 = n2 + 65536;         // wo: 262144/4
  int i = blockIdx.x * blockDim.x + threadIdx.x;
  int stride = gridDim.x * blockDim.x;
  for (; i < n3; i += stride) {
    const float4* src; ushort4* dst; int j;
    if (i < n1)      { src = (const float4*)x;  dst = (ushort4*)xb;  j = i; }
    else if (i < n2) { src = (const float4*)wq; dst = (ushort4*)wqb; j = i - n1; }
    else             { src = (const float4*)wo; dst = (ushort4*)wob; j = i - n2; }
    float4 v = src[j];
    ushort4 o;
    o.x = f2bf(v.x); o.y = f2bf(v.y); o.z = f2bf(v.z); o.w = f2bf(v.w);
    dst[j] = o;
  }
}

// ---------------- NT GEMM: C[M,N] = A[M,K] * B[N,K]^T (bf16 in, MFMA) -------
// R7-measured-best form: single-buffer 32 KB LDS (3 blocks/CU for gemm0's
// 768-block grid). Staging: global_load_lds width=16 into linear [128][64]
// LDS, XOR-swizzled source (c8 ^= row&7) + same XOR on ds_read.
// EPI==0: QKV projection epilogue -> scatter to q (x 0.125*log2e), k, vt layouts
// EPI==1: O projection, raw fp32 out + per-block LN partials (no sync)
template<int EPI>
__global__ __launch_bounds__(256, 2)
void gemm_nt(const u16* __restrict__ A, const u16* __restrict__ Bm, int K,
             float* __restrict__ outF,
             u16* __restrict__ qws, u16* __restrict__ kws, u16* __restrict__ vtws,
             float2* __restrict__ partials)
{
  __shared__ u16 As[128][64];
  __shared__ u16 Bs[128][64];
  const int tid = threadIdx.x;
  const int lane = tid & 63;
  const int wv = tid >> 6;
  const int wr = wv >> 1, wc = wv & 1;
  const int bm = blockIdx.x, bn = blockIdx.y;
  const int l15 = lane & 15, lg = lane >> 4;
  const int srow8 = lane >> 3;   // 0..7 within an 8-row staging stripe
  const int sc8 = lane & 7;      // 16B column within row

  f32x4 acc[4][4];
  #pragma unroll
  for (int i = 0; i < 4; i++)
    #pragma unroll
    for (int j = 0; j < 4; j++) acc[i][j] = (f32x4){0.f, 0.f, 0.f, 0.f};

  for (int kk = 0; kk < K; kk += 64) {
    // ---- async stage A/B tiles: 4 issues/wave each, 1KB per wave-issue ----
    #pragma unroll
    for (int i = 0; i < 4; i++) {
      int r0 = (i * 4 + wv) * 8;
      int r = r0 + srow8;
      int cs = sc8 ^ (r & 7);
      const u16* ga = A + (size_t)(bm * 128 + r) * K + kk + cs * 8;
      __builtin_amdgcn_global_load_lds((gv_t*)ga, (lv_t*)&As[r0][0], 16, 0, 0);
      const u16* gb = Bm + (size_t)(bn * 128 + r) * K + kk + cs * 8;
      __builtin_amdgcn_global_load_lds((gv_t*)gb, (lv_t*)&Bs[r0][0], 16, 0, 0);
    }
    __syncthreads();   // compiler inserts vmcnt(0) drain before barrier
    #pragma unroll
    for (int kc = 0; kc < 2; kc++) {
      short8 af[4], bf[4];
      #pragma unroll
      for (int mi = 0; mi < 4; mi++) {
        int ra = wr * 64 + mi * 16 + l15;
        af[mi] = *(const short8*)&As[ra][((kc * 4 + lg) ^ (ra & 7)) * 8];
      }
      #pragma unroll
      for (int ni = 0; ni < 4; ni++) {
        int rb = wc * 64 + ni * 16 + l15;
        bf[ni] = *(const short8*)&Bs[rb][((kc * 4 + lg) ^ (rb & 7)) * 8];
      }
      #pragma unroll
      for (int mi = 0; mi < 4; mi++)
        #pragma unroll
        for (int ni = 0; ni < 4; ni++)
          acc[mi][ni] = __builtin_amdgcn_mfma_f32_16x16x32_bf16(af[mi], bf[ni], acc[mi][ni], 0, 0, 0);
    }
    __syncthreads();
  }

  // ---- epilogue; C-frag: col = lane&15, row = (lane>>4)*4 + r ----
  if (EPI == 0) {
    #pragma unroll
    for (int mi = 0; mi < 4; mi++) {
      int rowg = bm * 128 + wr * 64 + mi * 16 + lg * 4;
      #pragma unroll
      for (int ni = 0; ni < 4; ni++) {
        int colg = bn * 128 + wc * 64 + ni * 16 + l15;
        #pragma unroll
        for (int r = 0; r < 4; r++) {
          int rg = rowg + r;
          float v = acc[mi][ni][r];
          int b = rg >> 10, s = rg & 1023;
          int h = colg / 192, c = colg - h * 192;
          int bh = b * 8 + h;
          if (c < 64)
            qws[((size_t)(bh * 1024 + s)) * 64 + c] = f2bf(v * 0.18033688f); // 0.125*log2(e)
          else if (c < 128)
            kws[((size_t)(bh * 1024 + s)) * 64 + (c - 64)] = f2bf(v);
          else
            vtws[((size_t)(bh * 64 + (c - 128))) * 1024 + s] = f2bf(v);
        }
      }
    }
  } else {
    // raw output write + per-block LN partial sums (plain store, no sync)
    float s1 = 0.f, s2 = 0.f;
    #pragma unroll
    for (int mi = 0; mi < 4; mi++) {
      int rowg = bm * 128 + wr * 64 + mi * 16 + lg * 4;
      #pragma unroll
      for (int ni = 0; ni < 4; ni++) {
        int colg = bn * 128 + wc * 64 + ni * 16 + l15;
        #pragma unroll
        for (int r = 0; r < 4; r++) {
          float v = acc[mi][ni][r];
          s1 += v; s2 += v * v;
          outF[(size_t)(rowg + r) * 512 + colg] = v;
        }
      }
    }
    #pragma unroll
    for (int off = 1; off < 64; off <<= 1) {
      s1 += __shfl_xor(s1, off);
      s2 += __shfl_xor(s2, off);
    }
    __shared__ float r1[4], r2[4];
    if (lane == 0) { r1[wv] = s1; r2[wv] = s2; }
    __syncthreads();
    if (tid == 0) {
      float t1 = r1[0] + r1[1] + r1[2] + r1[3];
      float t2 = r2[0] + r2[1] + r2[2] + r2[3];
      partials[bm * 4 + bn] = make_float2(t1, t2);
    }
  }
}

// ---------------- Flash attention, 32x32 swapped-QK^T, register-only P -----
// (R7 measured-best: 83.0 us total.) 256 blocks = 64 bh * 4 q-tiles of 256
// rows (XCD-swizzled: one bh per XCD). 8 waves * 32 q rows share one K/V
// double-buffer. Logits in log2 units (Q pre-scaled by 0.125*log2e).
__global__ __launch_bounds__(512, 4)
void attn_kernel(const u16* __restrict__ qws, const u16* __restrict__ kws,
                 const u16* __restrict__ vtws, u16* __restrict__ vals)
{
  __shared__ __align__(16) u16 Ksm[2][64][72];   // K tile [k][d], dbuf
  __shared__ __align__(16) u16 Vsm[2][64][72];   // V tile [d][k], dbuf
  const int tid = threadIdx.x;
  const int lane = tid & 63;
  const int wq = tid >> 6;          // wave id 0..7, 32 q rows each
  const int l31 = lane & 31;
  const int hi = lane >> 5;
  // XCD swizzle: 256 blocks -> 32 consecutive logical blocks per XCD
  const int logical = (blockIdx.x & 7) * 32 + (blockIdx.x >> 3);
  const int bh = logical >> 2;
  const int q0 = (logical & 3) * 256;

  // ---- Q B-frags from global: col=q=l31, k-dim d = 16j+8hi+e ----
  short8 qf[4];
  {
    const u16* qp = qws + ((size_t)bh * 1024 + q0 + wq * 32 + l31) * 64 + 8 * hi;
    #pragma unroll
    for (int j = 0; j < 4; j++) qf[j] = *(const short8*)(qp + 16 * j);
  }

  // ---- stage K/V tile 0 (512 threads: one uint4 each per tile) ----
  const int srow = tid >> 3;             // 0..63
  const int sc8 = (tid & 7) * 8;
  uint4 kreg, vreg;
  kreg = *(const uint4*)(kws + ((size_t)bh * 1024 + srow) * 64 + sc8);
  vreg = *(const uint4*)(vtws + ((size_t)(bh * 64 + srow)) * 1024 + sc8);
  *(uint4*)&Ksm[0][srow][sc8] = kreg;
  *(uint4*)&Vsm[0][srow][sc8] = vreg;
  __syncthreads();

  f32x16 o[2];
  #pragma unroll
  for (int r = 0; r < 16; r++) { o[0][r] = 0.f; o[1][r] = 0.f; }
  float m = -1e30f, l = 0.f;

  for (int t = 0; t < 16; t++) {
    const int cur = t & 1;
    // T14: issue next-tile global loads first (latency hides under compute)
    if (t < 15) {
      int kv = (t + 1) * 64;
      kreg = *(const uint4*)(kws + ((size_t)bh * 1024 + kv + srow) * 64 + sc8);
      vreg = *(const uint4*)(vtws + ((size_t)(bh * 64 + srow)) * 1024 + kv + sc8);
    }

    // ---- S^T = K * Q^T: C[row=k_local][col=q=l31] per 32-key subtile ----
    f32x16 stv[2];
    __builtin_amdgcn_s_setprio(1);
    #pragma unroll
    for (int s2 = 0; s2 < 2; s2++) {
      f32x16 c;
      #pragma unroll
      for (int r = 0; r < 16; r++) c[r] = 0.f;
      #pragma unroll
      for (int j = 0; j < 4; j++) {
        short8 kf = *(const short8*)&Ksm[cur][s2 * 32 + l31][16 * j + 8 * hi];
        c = __builtin_amdgcn_mfma_f32_32x32x16_bf16(kf, qf[j], c, 0, 0, 0);
      }
      stv[s2] = c;
    }
    __builtin_amdgcn_s_setprio(0);

    // ---- online softmax: lane owns q=l31, 32 of 64 k's (other half at lane^32)
    float mx[16];
    #pragma unroll
    for (int r = 0; r < 16; r++) mx[r] = fmaxf(stv[0][r], stv[1][r]);
    #pragma unroll
    for (int w = 8; w >= 1; w >>= 1)
      #pragma unroll
      for (int r = 0; r < w; r++) mx[r] = fmaxf(mx[r], mx[r + w]);
    float pm = fmaxf(mx[0], __shfl_xor(mx[0], 32));

    // T13 defer-max (log2 units)
    if (!__all(pm - m <= 10.0f)) {
      float mn = fmaxf(m, pm);
      float al = fast_exp2(m - mn);
      m = mn; l *= al;
      #pragma unroll
      for (int reg = 0; reg < 16; reg++) {
        int qrow = (reg & 3) + 8 * (reg >> 2) + 4 * hi;
        float alo = __shfl(al, qrow);
        o[0][reg] *= alo; o[1][reg] *= alo;
      }
    }

    unsigned pk[16];
    float ps[16];
    #pragma unroll
    for (int s2 = 0; s2 < 2; s2++)
      #pragma unroll
      for (int j = 0; j < 8; j++) {
        float p0 = fast_exp2(stv[s2][2 * j] - m);
        float p1 = fast_exp2(stv[s2][2 * j + 1] - m);
        ps[s2 * 8 + j] = p0 + p1;
        pk[s2 * 8 + j] = cvt_pk_bf16(p0, p1);
      }
    #pragma unroll
    for (int w = 8; w >= 1; w >>= 1)
      #pragma unroll
      for (int r = 0; r < w; r++) ps[r] += ps[r + w];
    l += ps[0] + __shfl_xor(ps[0], 32);

    // ---- P redistribution: 8 permlane32_swap build PV A-frags in-register ----
    short8 pa[4];
    #pragma unroll
    for (int cc = 0; cc < 4; cc++) {
      int base = (cc >> 1) * 8 + (cc & 1) * 4;
      unsigned a0 = pk[base + 0], a2 = pk[base + 2];
      unsigned a1 = pk[base + 1], a3 = pk[base + 3];
      asm volatile("v_permlane32_swap_b32 %0, %1" : "+v"(a0), "+v"(a2));
      asm volatile("v_permlane32_swap_b32 %0, %1" : "+v"(a1), "+v"(a3));
      union { unsigned u[4]; short8 s8; } uu;
      uu.u[0] = a0; uu.u[1] = a1; uu.u[2] = a2; uu.u[3] = a3;
      pa[cc] = uu.s8;
    }

    // ---- O += P * V : A=P[q][k], B=V[k][d] (from Vt rows) ----
    __builtin_amdgcn_s_setprio(1);
    #pragma unroll
    for (int dh = 0; dh < 2; dh++)
      #pragma unroll
      for (int cc = 0; cc < 4; cc++) {
        short8 vf = *(const short8*)&Vsm[cur][dh * 32 + l31][16 * cc + 8 * hi];
        o[dh] = __builtin_amdgcn_mfma_f32_32x32x16_bf16(pa[cc], vf, o[dh], 0, 0, 0);
      }
    __builtin_amdgcn_s_setprio(0);

    // ---- write next tile into other buffer ----
    if (t < 15) {
      *(uint4*)&Ksm[cur ^ 1][srow][sc8] = kreg;
      *(uint4*)&Vsm[cur ^ 1][srow][sc8] = vreg;
    }
    __syncthreads();
  }

  // ---- epilogue: vals[b, s, h*64+d] bf16 ----
  const int b = bh >> 3, h = bh & 7;
  #pragma unroll
  for (int reg = 0; reg < 16; reg++) {
    int qrow = (reg & 3) + 8 * (reg >> 2) + 4 * hi;
    float linv = 1.0f / __shfl(l, qrow);
    size_t grow = (size_t)(b * 1024 + q0 + wq * 32 + qrow) * 512 + h * 64;
    vals[grow + l31]      = f2bf(o[0][reg] * linv);
    vals[grow + 32 + l31] = f2bf(o[1][reg] * linv);
  }
}

// ------- LayerNorm: each block reduces its batch's 32 partials, normalizes --
__global__ void ln_norm2(float* __restrict__ o, const float2* __restrict__ partials) {
  const int blk = blockIdx.x;        // 2048 blocks; 256 per batch
  const int b = blk >> 8;
  const int lane = threadIdx.x & 63;
  float s1 = 0.f, s2 = 0.f;
  if (lane < 32) {
    float2 p = partials[b * 32 + lane];
    s1 = p.x; s2 = p.y;
  }
  #pragma unroll
  for (int off = 1; off < 64; off <<= 1) {
    s1 += __shfl_xor(s1, off);
    s2 += __shfl_xor(s2, off);
  }
  float mu = s1 / 524288.f;
  float rs = rsqrtf(s2 / 524288.f - mu * mu + 1e-5f);
  const int base = blk * 512;        // 512 float4 per block
  #pragma unroll
  for (int k = 0; k < 2; k++) {
    int i = base + threadIdx.x + k * 256;
    float4 v = ((const float4*)o)[i];
    v.x = (v.x - mu) * rs; v.y = (v.y - mu) * rs;
    v.z = (v.z - mu) * rs; v.w = (v.w - mu) * rs;
    ((float4*)o)[i] = v;
  }
}

extern "C" void kernel_launch(void* const* d_in, const int* in_sizes, int n_in,
                              void* d_out, int out_size, void* d_ws, size_t ws_size,
                              hipStream_t stream) {
  const float* x = (const float*)d_in[0];
  const float* wqkv = (const float*)d_in[1];
  const float* wo = (const float*)d_in[2];
  float* out = (float*)d_out;
  char* ws = (char*)d_ws;

  u16* xb        = (u16*)(ws + 0);          // 8192*512   bf16 =  8,388,608 B
  u16* wqb       = (u16*)(ws + 8388608);    // 1536*512   bf16 =  1,572,864 B
  u16* wob       = (u16*)(ws + 9961472);    // 512*512    bf16 =    524,288 B
  u16* qws       = (u16*)(ws + 10485760);   // [bh,1024,64]    =  8,388,608 B
  u16* kws       = (u16*)(ws + 18874368);   // [bh,1024,64]    =  8,388,608 B
  u16* vtws      = (u16*)(ws + 27262976);   // [bh,64,1024]    =  8,388,608 B
  u16* vals      = (u16*)(ws + 35651584);   // [8192,512] bf16 =  8,388,608 B
  float2* parts  = (float2*)(ws + 44040192);// 256 float2 = 2 KB

  cvt_all<<<1280, 256, 0, stream>>>(x, wqkv, wo, xb, wqb, wob);

  dim3 g1(64, 12);
  gemm_nt<0><<<g1, 256, 0, stream>>>(xb, wqb, 512, nullptr, qws, kws, vtws, nullptr);

  attn_kernel<<<256, 512, 0, stream>>>(qws, kws, vtws, vals);

  dim3 g2(64, 4);
  gemm_nt<1><<<g2, 256, 0, stream>>>(vals, wob, 512, out, nullptr, nullptr, nullptr, parts);

  ln_norm2<<<2048, 256, 0, stream>>>(out, parts);
}

// Round 13
// 81.632 us; speedup vs baseline: 1.1280x; 1.0100x over previous
//
#include <hip/hip_runtime.h>
#include <hip/hip_bf16.h>
#include <math.h>

// Problem constants
#define BB 8
#define SS 1024
#define INDIM 512
#define ED 512
#define NH 8
#define HD 64

typedef __attribute__((ext_vector_type(8))) short short8;
typedef __attribute__((ext_vector_type(4))) float f32x4;
typedef __attribute__((ext_vector_type(16))) float f32x16;
typedef unsigned short u16;

typedef __attribute__((address_space(1))) const void gv_t;
typedef __attribute__((address_space(3))) void lv_t;

static __device__ __forceinline__ u16 f2bf(float f) {
  union { float f; unsigned u; } v; v.f = f;
  unsigned r = v.u + 0x7fffu + ((v.u >> 16) & 1u);
  return (u16)(r >> 16);
}
static __device__ __forceinline__ float bf2f(u16 b) {
  union { unsigned u; float f; } v; v.u = (unsigned)b << 16; return v.f;
}

// packed f32x2 -> bf16x2 (RTNE), single VOP3 instr on gfx950
static __device__ __forceinline__ unsigned cvt_pk_bf16(float a, float b) {
  unsigned r;
  asm("v_cvt_pk_bf16_f32 %0, %1, %2" : "=v"(r) : "v"(a), "v"(b));
  return r;
}
// v_exp_f32 = 2^x natively
static __device__ __forceinline__ float fast_exp2(float x) {
  float r; asm("v_exp_f32 %0, %1" : "=v"(r) : "v"(x)); return r;
}

// ---------------- fp32 -> bf16 convert (all three inputs, one launch) ------
__global__ void cvt_all(const float* __restrict__ x, const float* __restrict__ wq,
                        const float* __restrict__ wo, u16* __restrict__ xb,
                        u16* __restrict__ wqb, u16* __restrict__ wob) {
  const int n1 = 1048576;            // x: 4194304/4 quads
  const int n2 = n1 + 196608;        // wqkv: 786432/4
  const int n3 = n2 + 65536;         // wo: 262144/4
  int i = blockIdx.x * blockDim.x + threadIdx.x;
  int stride = gridDim.x * blockDim.x;
  for (; i < n3; i += stride) {
    const float4* src; ushort4* dst; int j;
    if (i < n1)      { src = (const float4*)x;  dst = (ushort4*)xb;  j = i; }
    else if (i < n2) { src = (const float4*)wq; dst = (ushort4*)wqb; j = i - n1; }
    else             { src = (const float4*)wo; dst = (ushort4*)wob; j = i - n2; }
    float4 v = src[j];
    ushort4 o;
    o.x = f2bf(v.x); o.y = f2bf(v.y); o.z = f2bf(v.z); o.w = f2bf(v.w);
    dst[j] = o;
  }
}

// ---------------- NT GEMM: C[M,N] = A[M,K] * B[N,K]^T (bf16 in, MFMA) -------
// R7-measured-best form: single-buffer 32 KB LDS (3 blocks/CU for gemm0's
// 768-block grid). Staging: global_load_lds width=16 into linear [128][64]
// LDS, XOR-swizzled source (c8 ^= row&7) + same XOR on ds_read.
// EPI==0: QKV projection epilogue -> scatter to q (x 0.125*log2e), k, vt layouts
// EPI==1: O projection, bf16 out (via outB) + per-block LN partials (no sync);
//         LN stats computed from fp32 accumulators BEFORE rounding.
template<int EPI>
__global__ __launch_bounds__(256, 2)
void gemm_nt(const u16* __restrict__ A, const u16* __restrict__ Bm, int K,
             u16* __restrict__ outB,
             u16* __restrict__ qws, u16* __restrict__ kws, u16* __restrict__ vtws,
             float2* __restrict__ partials)
{
  __shared__ u16 As[128][64];
  __shared__ u16 Bs[128][64];
  const int tid = threadIdx.x;
  const int lane = tid & 63;
  const int wv = tid >> 6;
  const int wr = wv >> 1, wc = wv & 1;
  const int bm = blockIdx.x, bn = blockIdx.y;
  const int l15 = lane & 15, lg = lane >> 4;
  const int srow8 = lane >> 3;   // 0..7 within an 8-row staging stripe
  const int sc8 = lane & 7;      // 16B column within row

  f32x4 acc[4][4];
  #pragma unroll
  for (int i = 0; i < 4; i++)
    #pragma unroll
    for (int j = 0; j < 4; j++) acc[i][j] = (f32x4){0.f, 0.f, 0.f, 0.f};

  for (int kk = 0; kk < K; kk += 64) {
    // ---- async stage A/B tiles: 4 issues/wave each, 1KB per wave-issue ----
    #pragma unroll
    for (int i = 0; i < 4; i++) {
      int r0 = (i * 4 + wv) * 8;
      int r = r0 + srow8;
      int cs = sc8 ^ (r & 7);
      const u16* ga = A + (size_t)(bm * 128 + r) * K + kk + cs * 8;
      __builtin_amdgcn_global_load_lds((gv_t*)ga, (lv_t*)&As[r0][0], 16, 0, 0);
      const u16* gb = Bm + (size_t)(bn * 128 + r) * K + kk + cs * 8;
      __builtin_amdgcn_global_load_lds((gv_t*)gb, (lv_t*)&Bs[r0][0], 16, 0, 0);
    }
    __syncthreads();   // compiler inserts vmcnt(0) drain before barrier
    #pragma unroll
    for (int kc = 0; kc < 2; kc++) {
      short8 af[4], bf[4];
      #pragma unroll
      for (int mi = 0; mi < 4; mi++) {
        int ra = wr * 64 + mi * 16 + l15;
        af[mi] = *(const short8*)&As[ra][((kc * 4 + lg) ^ (ra & 7)) * 8];
      }
      #pragma unroll
      for (int ni = 0; ni < 4; ni++) {
        int rb = wc * 64 + ni * 16 + l15;
        bf[ni] = *(const short8*)&Bs[rb][((kc * 4 + lg) ^ (rb & 7)) * 8];
      }
      #pragma unroll
      for (int mi = 0; mi < 4; mi++)
        #pragma unroll
        for (int ni = 0; ni < 4; ni++)
          acc[mi][ni] = __builtin_amdgcn_mfma_f32_16x16x32_bf16(af[mi], bf[ni], acc[mi][ni], 0, 0, 0);
    }
    __syncthreads();
  }

  // ---- epilogue; C-frag: col = lane&15, row = (lane>>4)*4 + r ----
  if (EPI == 0) {
    #pragma unroll
    for (int mi = 0; mi < 4; mi++) {
      int rowg = bm * 128 + wr * 64 + mi * 16 + lg * 4;
      #pragma unroll
      for (int ni = 0; ni < 4; ni++) {
        int colg = bn * 128 + wc * 64 + ni * 16 + l15;
        #pragma unroll
        for (int r = 0; r < 4; r++) {
          int rg = rowg + r;
          float v = acc[mi][ni][r];
          int b = rg >> 10, s = rg & 1023;
          int h = colg / 192, c = colg - h * 192;
          int bh = b * 8 + h;
          if (c < 64)
            qws[((size_t)(bh * 1024 + s)) * 64 + c] = f2bf(v * 0.18033688f); // 0.125*log2(e)
          else if (c < 128)
            kws[((size_t)(bh * 1024 + s)) * 64 + (c - 64)] = f2bf(v);
          else
            vtws[((size_t)(bh * 64 + (c - 128))) * 1024 + s] = f2bf(v);
        }
      }
    }
  } else {
    // bf16 output write + per-block LN partials from fp32 accumulators
    float s1 = 0.f, s2 = 0.f;
    #pragma unroll
    for (int mi = 0; mi < 4; mi++) {
      int rowg = bm * 128 + wr * 64 + mi * 16 + lg * 4;
      #pragma unroll
      for (int ni = 0; ni < 4; ni++) {
        int colg = bn * 128 + wc * 64 + ni * 16 + l15;
        #pragma unroll
        for (int r = 0; r < 4; r++) {
          float v = acc[mi][ni][r];
          s1 += v; s2 += v * v;
          outB[(size_t)(rowg + r) * 512 + colg] = f2bf(v);
        }
      }
    }
    #pragma unroll
    for (int off = 1; off < 64; off <<= 1) {
      s1 += __shfl_xor(s1, off);
      s2 += __shfl_xor(s2, off);
    }
    __shared__ float r1[4], r2[4];
    if (lane == 0) { r1[wv] = s1; r2[wv] = s2; }
    __syncthreads();
    if (tid == 0) {
      float t1 = r1[0] + r1[1] + r1[2] + r1[3];
      float t2 = r2[0] + r2[1] + r2[2] + r2[3];
      partials[bm * 4 + bn] = make_float2(t1, t2);
    }
  }
}

// ---------------- Flash attention, 32x32 swapped-QK^T, register-only P -----
// (R7/R12 measured-best: 82.5 us total.) 256 blocks = 64 bh * 4 q-tiles of
// 256 rows (XCD-swizzled: one bh per XCD). 8 waves * 32 q rows share one K/V
// double-buffer. Logits in log2 units (Q pre-scaled by 0.125*log2e).
__global__ __launch_bounds__(512, 4)
void attn_kernel(const u16* __restrict__ qws, const u16* __restrict__ kws,
                 const u16* __restrict__ vtws, u16* __restrict__ vals)
{
  __shared__ __align__(16) u16 Ksm[2][64][72];   // K tile [k][d], dbuf
  __shared__ __align__(16) u16 Vsm[2][64][72];   // V tile [d][k], dbuf
  const int tid = threadIdx.x;
  const int lane = tid & 63;
  const int wq = tid >> 6;          // wave id 0..7, 32 q rows each
  const int l31 = lane & 31;
  const int hi = lane >> 5;
  // XCD swizzle: 256 blocks -> 32 consecutive logical blocks per XCD
  const int logical = (blockIdx.x & 7) * 32 + (blockIdx.x >> 3);
  const int bh = logical >> 2;
  const int q0 = (logical & 3) * 256;

  // ---- Q B-frags from global: col=q=l31, k-dim d = 16j+8hi+e ----
  short8 qf[4];
  {
    const u16* qp = qws + ((size_t)bh * 1024 + q0 + wq * 32 + l31) * 64 + 8 * hi;
    #pragma unroll
    for (int j = 0; j < 4; j++) qf[j] = *(const short8*)(qp + 16 * j);
  }

  // ---- stage K/V tile 0 (512 threads: one uint4 each per tile) ----
  const int srow = tid >> 3;             // 0..63
  const int sc8 = (tid & 7) * 8;
  uint4 kreg, vreg;
  kreg = *(const uint4*)(kws + ((size_t)bh * 1024 + srow) * 64 + sc8);
  vreg = *(const uint4*)(vtws + ((size_t)(bh * 64 + srow)) * 1024 + sc8);
  *(uint4*)&Ksm[0][srow][sc8] = kreg;
  *(uint4*)&Vsm[0][srow][sc8] = vreg;
  __syncthreads();

  f32x16 o[2];
  #pragma unroll
  for (int r = 0; r < 16; r++) { o[0][r] = 0.f; o[1][r] = 0.f; }
  float m = -1e30f, l = 0.f;

  for (int t = 0; t < 16; t++) {
    const int cur = t & 1;
    // T14: issue next-tile global loads first (latency hides under compute)
    if (t < 15) {
      int kv = (t + 1) * 64;
      kreg = *(const uint4*)(kws + ((size_t)bh * 1024 + kv + srow) * 64 + sc8);
      vreg = *(const uint4*)(vtws + ((size_t)(bh * 64 + srow)) * 1024 + kv + sc8);
    }

    // ---- S^T = K * Q^T: C[row=k_local][col=q=l31] per 32-key subtile ----
    f32x16 stv[2];
    __builtin_amdgcn_s_setprio(1);
    #pragma unroll
    for (int s2 = 0; s2 < 2; s2++) {
      f32x16 c;
      #pragma unroll
      for (int r = 0; r < 16; r++) c[r] = 0.f;
      #pragma unroll
      for (int j = 0; j < 4; j++) {
        short8 kf = *(const short8*)&Ksm[cur][s2 * 32 + l31][16 * j + 8 * hi];
        c = __builtin_amdgcn_mfma_f32_32x32x16_bf16(kf, qf[j], c, 0, 0, 0);
      }
      stv[s2] = c;
    }
    __builtin_amdgcn_s_setprio(0);

    // ---- online softmax: lane owns q=l31, 32 of 64 k's (other half at lane^32)
    float mx[16];
    #pragma unroll
    for (int r = 0; r < 16; r++) mx[r] = fmaxf(stv[0][r], stv[1][r]);
    #pragma unroll
    for (int w = 8; w >= 1; w >>= 1)
      #pragma unroll
      for (int r = 0; r < w; r++) mx[r] = fmaxf(mx[r], mx[r + w]);
    float pm = fmaxf(mx[0], __shfl_xor(mx[0], 32));

    // T13 defer-max (log2 units)
    if (!__all(pm - m <= 10.0f)) {
      float mn = fmaxf(m, pm);
      float al = fast_exp2(m - mn);
      m = mn; l *= al;
      #pragma unroll
      for (int reg = 0; reg < 16; reg++) {
        int qrow = (reg & 3) + 8 * (reg >> 2) + 4 * hi;
        float alo = __shfl(al, qrow);
        o[0][reg] *= alo; o[1][reg] *= alo;
      }
    }

    unsigned pk[16];
    float ps[16];
    #pragma unroll
    for (int s2 = 0; s2 < 2; s2++)
      #pragma unroll
      for (int j = 0; j < 8; j++) {
        float p0 = fast_exp2(stv[s2][2 * j] - m);
        float p1 = fast_exp2(stv[s2][2 * j + 1] - m);
        ps[s2 * 8 + j] = p0 + p1;
        pk[s2 * 8 + j] = cvt_pk_bf16(p0, p1);
      }
    #pragma unroll
    for (int w = 8; w >= 1; w >>= 1)
      #pragma unroll
      for (int r = 0; r < w; r++) ps[r] += ps[r + w];
    l += ps[0] + __shfl_xor(ps[0], 32);

    // ---- P redistribution: 8 permlane32_swap build PV A-frags in-register ----
    short8 pa[4];
    #pragma unroll
    for (int cc = 0; cc < 4; cc++) {
      int base = (cc >> 1) * 8 + (cc & 1) * 4;
      unsigned a0 = pk[base + 0], a2 = pk[base + 2];
      unsigned a1 = pk[base + 1], a3 = pk[base + 3];
      asm volatile("v_permlane32_swap_b32 %0, %1" : "+v"(a0), "+v"(a2));
      asm volatile("v_permlane32_swap_b32 %0, %1" : "+v"(a1), "+v"(a3));
      union { unsigned u[4]; short8 s8; } uu;
      uu.u[0] = a0; uu.u[1] = a1; uu.u[2] = a2; uu.u[3] = a3;
      pa[cc] = uu.s8;
    }

    // ---- O += P * V : A=P[q][k], B=V[k][d] (from Vt rows) ----
    __builtin_amdgcn_s_setprio(1);
    #pragma unroll
    for (int dh = 0; dh < 2; dh++)
      #pragma unroll
      for (int cc = 0; cc < 4; cc++) {
        short8 vf = *(const short8*)&Vsm[cur][dh * 32 + l31][16 * cc + 8 * hi];
        o[dh] = __builtin_amdgcn_mfma_f32_32x32x16_bf16(pa[cc], vf, o[dh], 0, 0, 0);
      }
    __builtin_amdgcn_s_setprio(0);

    // ---- write next tile into other buffer ----
    if (t < 15) {
      *(uint4*)&Ksm[cur ^ 1][srow][sc8] = kreg;
      *(uint4*)&Vsm[cur ^ 1][srow][sc8] = vreg;
    }
    __syncthreads();
  }

  // ---- epilogue: vals[b, s, h*64+d] bf16 ----
  const int b = bh >> 3, h = bh & 7;
  #pragma unroll
  for (int reg = 0; reg < 16; reg++) {
    int qrow = (reg & 3) + 8 * (reg >> 2) + 4 * hi;
    float linv = 1.0f / __shfl(l, qrow);
    size_t grow = (size_t)(b * 1024 + q0 + wq * 32 + qrow) * 512 + h * 64;
    vals[grow + l31]      = f2bf(o[0][reg] * linv);
    vals[grow + 32 + l31] = f2bf(o[1][reg] * linv);
  }
}

// ------- LayerNorm: bf16 in (halved fetch), fp32 out ----------------------
// Each block re-reduces its batch's 32 partials (256 B), then normalizes its
// 2048-element chunk: read 8 bf16 (uint4) per thread, write 2 float4.
__global__ void ln_norm3(const u16* __restrict__ ob, float* __restrict__ o,
                         const float2* __restrict__ partials) {
  const int blk = blockIdx.x;        // 2048 blocks; 256 per batch
  const int b = blk >> 8;
  const int lane = threadIdx.x & 63;
  float s1 = 0.f, s2 = 0.f;
  if (lane < 32) {
    float2 p = partials[b * 32 + lane];
    s1 = p.x; s2 = p.y;
  }
  #pragma unroll
  for (int off = 1; off < 64; off <<= 1) {
    s1 += __shfl_xor(s1, off);
    s2 += __shfl_xor(s2, off);
  }
  float mu = s1 / 524288.f;
  float rs = rsqrtf(s2 / 524288.f - mu * mu + 1e-5f);
  const size_t i = (size_t)blk * 2048 + threadIdx.x * 8;
  uint4 v = *(const uint4*)(ob + i);
  float4 o0, o1;
  o0.x = (bf2f((u16)(v.x & 0xffff)) - mu) * rs;
  o0.y = (bf2f((u16)(v.x >> 16)) - mu) * rs;
  o0.z = (bf2f((u16)(v.y & 0xffff)) - mu) * rs;
  o0.w = (bf2f((u16)(v.y >> 16)) - mu) * rs;
  o1.x = (bf2f((u16)(v.z & 0xffff)) - mu) * rs;
  o1.y = (bf2f((u16)(v.z >> 16)) - mu) * rs;
  o1.z = (bf2f((u16)(v.w & 0xffff)) - mu) * rs;
  o1.w = (bf2f((u16)(v.w >> 16)) - mu) * rs;
  *(float4*)(o + i) = o0;
  *(float4*)(o + i + 4) = o1;
}

extern "C" void kernel_launch(void* const* d_in, const int* in_sizes, int n_in,
                              void* d_out, int out_size, void* d_ws, size_t ws_size,
                              hipStream_t stream) {
  const float* x = (const float*)d_in[0];
  const float* wqkv = (const float*)d_in[1];
  const float* wo = (const float*)d_in[2];
  float* out = (float*)d_out;
  char* ws = (char*)d_ws;

  u16* xb        = (u16*)(ws + 0);          // 8192*512   bf16 =  8,388,608 B
  u16* wqb       = (u16*)(ws + 8388608);    // 1536*512   bf16 =  1,572,864 B
  u16* wob       = (u16*)(ws + 9961472);    // 512*512    bf16 =    524,288 B
  u16* qws       = (u16*)(ws + 10485760);   // [bh,1024,64]    =  8,388,608 B
  u16* kws       = (u16*)(ws + 18874368);   // [bh,1024,64]    =  8,388,608 B
  u16* vtws      = (u16*)(ws + 27262976);   // [bh,64,1024]    =  8,388,608 B
  u16* vals      = (u16*)(ws + 35651584);   // [8192,512] bf16 =  8,388,608 B
  u16* outb      = (u16*)(ws + 44040192);   // [8192,512] bf16 =  8,388,608 B
  float2* parts  = (float2*)(ws + 52428800);// 256 float2 = 2 KB

  cvt_all<<<1280, 256, 0, stream>>>(x, wqkv, wo, xb, wqb, wob);

  dim3 g1(64, 12);
  gemm_nt<0><<<g1, 256, 0, stream>>>(xb, wqb, 512, nullptr, qws, kws, vtws, nullptr);

  attn_kernel<<<256, 512, 0, stream>>>(qws, kws, vtws, vals);

  dim3 g2(64, 4);
  gemm_nt<1><<<g2, 256, 0, stream>>>(vals, wob, 512, outb, nullptr, nullptr, nullptr, parts);

  ln_norm3<<<2048, 256, 0, stream>>>(outb, out, parts);
}